// Round 10
// baseline (186.051 us; speedup 1.0000x reference)
//
#include <hip/hip_runtime.h>
#include <hip/hip_bf16.h>
#include <math.h>

// Problem constants: B=2, T=2048, C=1024, H=16, D=64
#define BB 2
#define TT 2048
#define HH 16
#define DD 64
#define CC 1024
#define C3 3072

typedef __attribute__((ext_vector_type(8))) short bf16x8;
typedef __attribute__((ext_vector_type(4))) short bf16x4;
typedef __attribute__((ext_vector_type(4))) float f32x4;
typedef __attribute__((ext_vector_type(2))) unsigned int u32x2;

// round-to-nearest-even fp32 -> bf16 bits
__device__ __forceinline__ unsigned short f2bf(float f) {
  union { float f; unsigned u; } v; v.f = f;
  unsigned r = v.u + 0x7fffu + ((v.u >> 16) & 1u);
  return (unsigned short)(r >> 16);
}
// packed 2x fp32 -> bf16x2 (v_cvt_pk_bf16_f32 on gfx950), RNE
__device__ __forceinline__ unsigned pack2bf(float a, float b) {
  __hip_bfloat162 h = __float22bfloat162_rn(make_float2(a, b));
  union { __hip_bfloat162 h; unsigned u; } cv; cv.h = h;
  return cv.u;
}

// async global->LDS 16B copy (dest = wave-uniform base + lane*16)
__device__ __forceinline__ void async_cp16(const void* g, void* l) {
  __builtin_amdgcn_global_load_lds(
      (const __attribute__((address_space(1))) void*)g,
      (__attribute__((address_space(3))) void*)l, 16, 0, 0);
}

// ---------------------------------------------------------------------------
// prep: one launch does x->bf16 cvt + both weight transposes.
// ---------------------------------------------------------------------------
__global__ __launch_bounds__(256)
void prep(const float* __restrict__ x, const float* __restrict__ w_attn,
          const float* __restrict__ w_proj, unsigned short* __restrict__ xb,
          unsigned short* __restrict__ wat, unsigned short* __restrict__ wpt) {
  __shared__ __align__(16) float Ts[64][68];
  const int bx = blockIdx.x, tid = threadIdx.x;
  if (bx < 1024) {
    int i = bx * 256 + tid;
#pragma unroll
    for (int it = 0; it < 4; ++it, i += 262144) {
      const float4 v = ((const float4*)x)[i];
      bf16x4 o = {(short)f2bf(v.x), (short)f2bf(v.y),
                  (short)f2bf(v.z), (short)f2bf(v.w)};
      ((bf16x4*)xb)[i] = o;
    }
    return;
  }
  const float* W;
  unsigned short* WT;
  int Nd, bound, n0, k0;
  float s;
  if (bx < 1792) {
    const int bid = bx - 1024;
    W = w_attn; WT = wat; Nd = 3072; bound = 1024; s = 0.18033688f;  // 0.125*log2e
    n0 = (bid % 48) * 64; k0 = (bid / 48) * 64;
  } else {
    const int bid = bx - 1792;
    W = w_proj; WT = wpt; Nd = 1024; bound = 0; s = 1.0f;
    n0 = (bid % 16) * 64; k0 = (bid / 16) * 64;
  }
  const int rl = tid >> 4, c4 = tid & 15;
#pragma unroll
  for (int it = 0; it < 4; ++it) {
    const int r = it * 16 + rl;
    *(float4*)&Ts[r][c4 * 4] =
        *(const float4*)(W + (size_t)(k0 + r) * Nd + n0 + c4 * 4);
  }
  __syncthreads();
#pragma unroll
  for (int it = 0; it < 4; ++it) {
    const int n = it * 16 + rl;
    const float sc = (n0 + n < bound) ? s : 1.0f;
    bf16x4 o = {(short)f2bf(Ts[c4 * 4 + 0][n] * sc),
                (short)f2bf(Ts[c4 * 4 + 1][n] * sc),
                (short)f2bf(Ts[c4 * 4 + 2][n] * sc),
                (short)f2bf(Ts[c4 * 4 + 3][n] * sc)};
    *(bf16x4*)(WT + (size_t)(n0 + n) * CC + k0 + c4 * 4) = o;
  }
}

// ---------------------------------------------------------------------------
// gemm_qkv: qkv = xb(4096x1024) @ wat(3072x1024)^T.  Tile 128x192, BK=32,
// 4 waves side-by-side in n (48 cols each), 24 MFMA/wave/iter, dbuf LDS.
// bf16 out; cols>=2048 (V) written transposed into vt[(b*16+h)*64+d][t].
// ---------------------------------------------------------------------------
__global__ __launch_bounds__(256, 2)
void gemm_qkv(const unsigned short* __restrict__ A,
              const unsigned short* __restrict__ BT,
              unsigned short* __restrict__ Cb,
              unsigned short* __restrict__ Vout) {
  __shared__ __align__(16) unsigned short As[2 * 128 * 32];  // 16 KB
  __shared__ __align__(16) unsigned short Bs[2 * 192 * 32];  // 24 KB

  const int tid = threadIdx.x;
  const int w = tid >> 6, lane = tid & 63;
  const int l15 = lane & 15, quad = lane >> 4;
  const int row0 = blockIdx.y * 128, col0 = blockIdx.x * 192;

  const int ca0 = tid, ca1 = tid + 256;
  const int ra0 = ca0 >> 2, ka0 = ((ca0 & 3) ^ ((ca0 >> 3) & 3)) * 8;
  const int ra1 = ca1 >> 2, ka1 = ((ca1 & 3) ^ ((ca1 >> 3) & 3)) * 8;
  const unsigned short* gA0 = A + (size_t)(row0 + ra0) * CC + ka0;
  const unsigned short* gA1 = A + (size_t)(row0 + ra1) * CC + ka1;
  const int cb0 = tid, cb1 = tid + 256, cb2 = tid + 512;
  const int rb0 = cb0 >> 2, kb0 = ((cb0 & 3) ^ ((cb0 >> 3) & 3)) * 8;
  const int rb1 = cb1 >> 2, kb1 = ((cb1 & 3) ^ ((cb1 >> 3) & 3)) * 8;
  const int rb2 = cb2 >> 2, kb2 = ((cb2 & 3) ^ ((cb2 >> 3) & 3)) * 8;
  const unsigned short* gB0 = BT + (size_t)(col0 + rb0) * CC + kb0;
  const unsigned short* gB1 = BT + (size_t)(col0 + rb1) * CC + kb1;
  const unsigned short* gB2 = BT + (size_t)(col0 + rb2) * CC + kb2;
  const int la0 = tid * 16, la1 = tid * 16 + 4096;
  const int lb0 = tid * 16, lb1 = tid * 16 + 4096, lb2 = tid * 16 + 8192;

  const int fro = l15 * 64 + 16 * (quad ^ ((l15 >> 1) & 3));

  f32x4 acc[8][3];
#pragma unroll
  for (int i = 0; i < 8; ++i)
#pragma unroll
    for (int j = 0; j < 3; ++j) acc[i][j] = (f32x4){0.f, 0.f, 0.f, 0.f};

  async_cp16(gA0, (char*)As + la0);
  async_cp16(gA1, (char*)As + la1);
  async_cp16(gB0, (char*)Bs + lb0);
  async_cp16(gB1, (char*)Bs + lb1);
  async_cp16(gB2, (char*)Bs + lb2);

  for (int i = 0; i < 32; ++i) {
    const int cur = i & 1;
    __syncthreads();

    if (i + 1 < 32) {
      const int k1 = (i + 1) * 32;
      const int ab = (cur ^ 1) * 8192, bb = (cur ^ 1) * 12288;
      async_cp16(gA0 + k1, (char*)As + ab + la0);
      async_cp16(gA1 + k1, (char*)As + ab + la1);
      async_cp16(gB0 + k1, (char*)Bs + bb + lb0);
      async_cp16(gB1 + k1, (char*)Bs + bb + lb1);
      async_cp16(gB2 + k1, (char*)Bs + bb + lb2);
    }

    const char* fA = (const char*)As + cur * 8192 + fro;
    const char* fB = (const char*)Bs + cur * 12288 + w * 3072 + fro;

    bf16x8 af[8], bf[3];
#pragma unroll
    for (int mt = 0; mt < 8; ++mt) af[mt] = *(const bf16x8*)(fA + mt * 1024);
#pragma unroll
    for (int nt = 0; nt < 3; ++nt) bf[nt] = *(const bf16x8*)(fB + nt * 1024);
#pragma unroll
    for (int mt = 0; mt < 8; ++mt)
#pragma unroll
      for (int nt = 0; nt < 3; ++nt)
        acc[mt][nt] = __builtin_amdgcn_mfma_f32_16x16x32_bf16(
            af[mt], bf[nt], acc[mt][nt], 0, 0, 0);
  }

#pragma unroll
  for (int mt = 0; mt < 8; ++mt) {
    const int rbase = row0 + mt * 16 + quad * 4;
#pragma unroll
    for (int nt = 0; nt < 3; ++nt) {
      const int colb = col0 + w * 48 + nt * 16;  // wave-uniform
      if (colb >= 2048) {
        const int bq = rbase >> 11, t0 = rbase & 2047;
        const int d = colb + l15 - 2048;
        bf16x4 o = {(short)f2bf(acc[mt][nt][0]), (short)f2bf(acc[mt][nt][1]),
                    (short)f2bf(acc[mt][nt][2]), (short)f2bf(acc[mt][nt][3])};
        *(bf16x4*)(Vout + (((size_t)(bq << 10) + d) << 11) + t0) = o;
      } else {
        const int col = colb + l15;
#pragma unroll
        for (int r = 0; r < 4; ++r)
          Cb[(size_t)(rbase + r) * C3 + col] = f2bf(acc[mt][nt][r]);
      }
    }
  }
}

// ---------------------------------------------------------------------------
// gemm_out: out(4096x1024 fp32) = yb(4096x1024) @ wpt(1024x1024)^T.
// Tile 64x128, BK=64 (16 iters x 16 MFMA/wave), waves 2x2, dbuf LDS.
// ---------------------------------------------------------------------------
__global__ __launch_bounds__(256, 2)
void gemm_out(const unsigned short* __restrict__ A,
              const unsigned short* __restrict__ BT,
              float* __restrict__ Cf) {
  __shared__ __align__(16) unsigned short As[2 * 64 * 64];    // 16 KB
  __shared__ __align__(16) unsigned short Bs[2 * 128 * 64];   // 32 KB

  const int tid = threadIdx.x;
  const int w = tid >> 6, lane = tid & 63;
  const int l15 = lane & 15, quad = lane >> 4;
  const int wm = w >> 1, wn = w & 1;
  const int row0 = blockIdx.y * 64, col0 = blockIdx.x * 128;

  const int ca0 = tid, ca1 = tid + 256;
  const int ra0 = ca0 >> 3, ka0 = ((ca0 & 7) ^ ((ca0 >> 3) & 7)) * 8;
  const int ra1 = ca1 >> 3, ka1 = ((ca1 & 7) ^ ((ca1 >> 3) & 7)) * 8;
  const unsigned short* gA0 = A + (size_t)(row0 + ra0) * CC + ka0;
  const unsigned short* gA1 = A + (size_t)(row0 + ra1) * CC + ka1;
  const unsigned short* gB[4];
  int lb[4];
#pragma unroll
  for (int t = 0; t < 4; ++t) {
    const int c = tid + t * 256;
    const int rb = c >> 3, kb = ((c & 7) ^ ((c >> 3) & 7)) * 8;
    gB[t] = BT + (size_t)(col0 + rb) * CC + kb;
    lb[t] = c * 16;
  }
  const int la0 = tid * 16, la1 = tid * 16 + 4096;

  const int fro = l15 * 128 + ((quad ^ (l15 & 7)) << 4);

  f32x4 acc[2][4];
#pragma unroll
  for (int i = 0; i < 2; ++i)
#pragma unroll
    for (int j = 0; j < 4; ++j) acc[i][j] = (f32x4){0.f, 0.f, 0.f, 0.f};

  async_cp16(gA0, (char*)As + la0);
  async_cp16(gA1, (char*)As + la1);
#pragma unroll
  for (int t = 0; t < 4; ++t) async_cp16(gB[t], (char*)Bs + lb[t]);

  for (int i = 0; i < 16; ++i) {
    const int cur = i & 1;
    __syncthreads();

    if (i + 1 < 16) {
      const int k1 = (i + 1) * 64;
      const int ab = (cur ^ 1) * 8192, bb = (cur ^ 1) * 16384;
      async_cp16(gA0 + k1, (char*)As + ab + la0);
      async_cp16(gA1 + k1, (char*)As + ab + la1);
#pragma unroll
      for (int t = 0; t < 4; ++t) async_cp16(gB[t] + k1, (char*)Bs + bb + lb[t]);
    }

    const char* fA = (const char*)As + cur * 8192 + wm * 4096 + fro;
    const char* fB = (const char*)Bs + cur * 16384 + wn * 8192 + fro;

#pragma unroll
    for (int kh = 0; kh < 2; ++kh) {
      const int xo = kh * 64;
      bf16x8 af[2], bf[4];
#pragma unroll
      for (int mt = 0; mt < 2; ++mt)
        af[mt] = *(const bf16x8*)(fA + mt * 2048 + ((fro + xo) & 127) - (fro & 127));
#pragma unroll
      for (int nt = 0; nt < 4; ++nt)
        bf[nt] = *(const bf16x8*)(fB + nt * 2048 + ((fro + xo) & 127) - (fro & 127));
#pragma unroll
      for (int mt = 0; mt < 2; ++mt)
#pragma unroll
        for (int nt = 0; nt < 4; ++nt)
          acc[mt][nt] = __builtin_amdgcn_mfma_f32_16x16x32_bf16(
              af[mt], bf[nt], acc[mt][nt], 0, 0, 0);
    }
  }

#pragma unroll
  for (int mt = 0; mt < 2; ++mt) {
    const int rbase = row0 + wm * 32 + mt * 16 + quad * 4;
#pragma unroll
    for (int r = 0; r < 4; ++r) {
      float* cr = Cf + (size_t)(rbase + r) * CC + col0 + wn * 64 + l15;
#pragma unroll
      for (int nt = 0; nt < 4; ++nt) cr[nt * 16] = acc[mt][nt][r];
    }
  }
}

// ---------------------------------------------------------------------------
// MFMA flash attention, round-10: SOFTWARE-PIPELINED dual-stream K-loop.
// Iter j overlaps: {ds_read K_{j+1} + QK MFMA}  with  {exp/pack/PV of tile j}
// (independent streams -> MFMA and VALU pipes co-issue within one wave).
// Prefetch distance 2 for K (prologue stages K0,K1), 1 for V.
// Ps: ct-XOR swizzle (slot=(ct+l15)&3) -> <=2-way banks on write and read.
// Packed bf16 cvt via v_cvt_pk_bf16_f32.  Fixed-max base-2 softmax, XCD-
// aware grid, q-tile pairing unchanged.
// ---------------------------------------------------------------------------
__global__ __launch_bounds__(256)
void attn_mfma(const unsigned short* __restrict__ qkvb,
               const unsigned short* __restrict__ vt,
               unsigned short* __restrict__ y) {
  const int n = blockIdx.x;
  const int bh = (n & 7) + 8 * ((n >> 3) & 3);
  const int qpair = n >> 5;
  const int b = bh >> 4, h = bh & 15;
  const int tid = threadIdx.x;
  const int w = tid >> 6;
  const int lane = tid & 63;
  const int l15 = lane & 15, quad = lane >> 4;

  __shared__ __align__(16) char Kb[2 * 8192];
  __shared__ __align__(16) char Vb[2 * 8192];
  __shared__ __align__(16) unsigned short Ps[4 * 16 * 72];
  char* psw = (char*)(Ps + w * 16 * 72);

  const int lr = lane >> 3;
  const int lc = lane & 7;
  const int srcoff = ((lc ^ lr) << 4);
  const char* ksrc = (const char*)qkvb + ((size_t)(b * TT) * C3 + 1024 + h * 64) * 2;
  const char* vsrc = (const char*)vt + ((size_t)(b * HH + h) * DD * TT) * 2;

  const int fro = l15 * 128 + ((quad ^ (l15 & 7)) << 4);

  // Ps addressing (ct-XOR swizzle): write slot (ct+l15)&3, quad*8 within slot
  const int psrow = l15 * 144;
  // read: kh half, c = 2*kh + (quad>>1); addr = psrow + ((c+l15)&3)*32 + (quad&1)*16

  bf16x8 onesf;
#pragma unroll
  for (int jj = 0; jj < 8; ++jj) onesf[jj] = (short)0x3F80;

  for (int phase = 0; phase < 2; ++phase) {
    const int qt = phase == 0 ? 31 - qpair : qpair;

    if (phase) __syncthreads();  // all phase-0 LDS reads done before restage

    const unsigned short* qrow =
        qkvb + (size_t)(b * TT + qt * 64 + w * 16 + l15) * C3 + h * DD;
    bf16x8 qf0 = *(const bf16x8*)(qrow + quad * 8);
    bf16x8 qf1 = *(const bf16x8*)(qrow + 32 + quad * 8);

    f32x4 O[4];
#pragma unroll
    for (int dt = 0; dt < 4; ++dt) O[dt] = (f32x4){0.f, 0.f, 0.f, 0.f};
    f32x4 lacc = (f32x4){0.f, 0.f, 0.f, 0.f};

    // ---- prologue: stage K0,V0 (+K1), then compute S_0 ----
#pragma unroll
    for (int i = 0; i < 2; ++i) {
      async_cp16(ksrc + (size_t)(w * 16 + i * 8 + lr) * (C3 * 2) + srcoff,
                 Kb + w * 2048 + i * 1024);
      async_cp16(vsrc + (size_t)(w * 16 + i * 8 + lr) * (TT * 2) + srcoff,
                 Vb + w * 2048 + i * 1024);
    }
    if (qt >= 1) {
#pragma unroll
      for (int i = 0; i < 2; ++i)
        async_cp16(ksrc + (size_t)(64 + w * 16 + i * 8 + lr) * (C3 * 2) + srcoff,
                   Kb + 8192 + w * 2048 + i * 1024);
    }
    __syncthreads();

    f32x4 Scur[4];
    {
      const char* Kc = Kb;  // buf 0
#pragma unroll
      for (int ct = 0; ct < 4; ++ct) {
        bf16x8 k0 = *(const bf16x8*)(Kc + ct * 2048 + fro);
        bf16x8 k1 = *(const bf16x8*)(Kc + ct * 2048 + (fro ^ 64));
        f32x4 z = (f32x4){-12.f, -12.f, -12.f, -12.f};
        z = __builtin_amdgcn_mfma_f32_16x16x32_bf16(k0, qf0, z, 0, 0, 0);
        z = __builtin_amdgcn_mfma_f32_16x16x32_bf16(k1, qf1, z, 0, 0, 0);
        Scur[ct] = z;
      }
      if (qt == 0) {
#pragma unroll
        for (int ct = 0; ct < 4; ++ct)
#pragma unroll
          for (int r = 0; r < 4; ++r)
            if (16 * ct + quad * 4 + r > w * 16 + l15) Scur[ct][r] = -INFINITY;
      }
    }

    for (int j = 0; j <= qt; ++j) {
      __syncthreads();  // prefetches from iter j-1 landed; all waves done
                        // reading the buffers we overwrite below

      // ---- prefetch: K_{j+2} -> Kb[j&1], V_{j+1} -> Vb[(j+1)&1] ----
      if (j + 2 <= qt) {
        const int keyk = (j + 2) * 64;
        char* kd = Kb + (j & 1) * 8192 + w * 2048;
#pragma unroll
        for (int i = 0; i < 2; ++i)
          async_cp16(ksrc + (size_t)(keyk + w * 16 + i * 8 + lr) * (C3 * 2) + srcoff,
                     kd + i * 1024);
      }
      if (j + 1 <= qt) {
        const int keyv = (j + 1) * 64;
        char* vd = Vb + ((j + 1) & 1) * 8192 + w * 2048;
#pragma unroll
        for (int i = 0; i < 2; ++i)
          async_cp16(vsrc + (size_t)(w * 16 + i * 8 + lr) * (TT * 2) + keyv * 2 + srcoff,
                     vd + i * 1024);
      }

      // ---- stream A: S_{j+1} from Kb[(j+1)&1] (independent of stream B) ----
      f32x4 Snxt[4];
      const bool have_nxt = (j + 1 <= qt);
      if (have_nxt) {
        const char* Kc = Kb + ((j + 1) & 1) * 8192;
#pragma unroll
        for (int ct = 0; ct < 4; ++ct) {
          bf16x8 k0 = *(const bf16x8*)(Kc + ct * 2048 + fro);
          bf16x8 k1 = *(const bf16x8*)(Kc + ct * 2048 + (fro ^ 64));
          f32x4 z = (f32x4){-12.f, -12.f, -12.f, -12.f};
          z = __builtin_amdgcn_mfma_f32_16x16x32_bf16(k0, qf0, z, 0, 0, 0);
          z = __builtin_amdgcn_mfma_f32_16x16x32_bf16(k1, qf1, z, 0, 0, 0);
          Snxt[ct] = z;
        }
        if (j + 1 == qt) {  // causal mask on diagonal tile
#pragma unroll
          for (int ct = 0; ct < 4; ++ct)
#pragma unroll
            for (int r = 0; r < 4; ++r)
              if (16 * ct + quad * 4 + r > w * 16 + l15) Snxt[ct][r] = -INFINITY;
        }
      }

      // ---- stream B: exp/pack P_j -> Ps (swizzled), PV_j ----
#pragma unroll
      for (int ct = 0; ct < 4; ++ct) {
        u32x2 d;
        d[0] = pack2bf(exp2f(Scur[ct][0]), exp2f(Scur[ct][1]));
        d[1] = pack2bf(exp2f(Scur[ct][2]), exp2f(Scur[ct][3]));
        *(u32x2*)(psw + psrow + (((ct + l15) & 3) << 5) + quad * 8) = d;
      }

      bf16x8 pf0, pf1;
      {
        const int c0 = (quad >> 1), c1 = 2 + (quad >> 1);
        pf0 = *(const bf16x8*)(psw + psrow + (((c0 + l15) & 3) << 5) + ((quad & 1) << 4));
        pf1 = *(const bf16x8*)(psw + psrow + (((c1 + l15) & 3) << 5) + ((quad & 1) << 4));
      }

      lacc = __builtin_amdgcn_mfma_f32_16x16x32_bf16(onesf, pf0, lacc, 0, 0, 0);
      lacc = __builtin_amdgcn_mfma_f32_16x16x32_bf16(onesf, pf1, lacc, 0, 0, 0);
      const char* Vc = Vb + (j & 1) * 8192;
#pragma unroll
      for (int dt = 0; dt < 4; ++dt) {
        bf16x8 v0 = *(const bf16x8*)(Vc + dt * 2048 + fro);
        bf16x8 v1 = *(const bf16x8*)(Vc + dt * 2048 + (fro ^ 64));
        O[dt] = __builtin_amdgcn_mfma_f32_16x16x32_bf16(v0, pf0, O[dt], 0, 0, 0);
        O[dt] = __builtin_amdgcn_mfma_f32_16x16x32_bf16(v1, pf1, O[dt], 0, 0, 0);
      }

      if (have_nxt) {
#pragma unroll
        for (int ct = 0; ct < 4; ++ct) Scur[ct] = Snxt[ct];
      }
    }

    // ---- epilogue: lane holds O^T[d=dt*16+quad*4+r][q=l15]; l in lacc ----
    const float inv = 1.0f / lacc[0];
    unsigned short* yr =
        y + (size_t)(b * TT + qt * 64 + w * 16 + l15) * CC + h * DD + quad * 4;
#pragma unroll
    for (int dt = 0; dt < 4; ++dt) {
      bf16x4 o = {(short)f2bf(O[dt][0] * inv), (short)f2bf(O[dt][1] * inv),
                  (short)f2bf(O[dt][2] * inv), (short)f2bf(O[dt][3] * inv)};
      *(bf16x4*)(yr + dt * 16) = o;
    }
  }
}

// ---------------------------------------------------------------------------
extern "C" void kernel_launch(void* const* d_in, const int* in_sizes, int n_in,
                              void* d_out, int out_size, void* d_ws,
                              size_t ws_size, hipStream_t stream) {
  const float* x      = (const float*)d_in[0];
  const float* w_attn = (const float*)d_in[1];
  const float* w_proj = (const float*)d_in[2];
  float* out = (float*)d_out;

  unsigned short* xb   = (unsigned short*)d_ws;
  unsigned short* wat  = xb + (size_t)4096 * 1024;
  unsigned short* wpt  = wat + (size_t)3072 * 1024;
  unsigned short* qkvb = wpt + (size_t)1024 * 1024;
  unsigned short* vt   = qkvb + (size_t)4096 * 3072;
  unsigned short* yb   = vt + (size_t)BB * HH * DD * TT;

  dim3 blk(256);

  prep<<<2048, blk, 0, stream>>>(x, w_attn, w_proj, xb, wat, wpt);

  // qkv = xb @ watT; q pre-scaled via wat; v written transposed into vt
  gemm_qkv<<<dim3(C3 / 192, (BB * TT) / 128), blk, 0, stream>>>(
      xb, wat, qkvb, vt);

  attn_mfma<<<dim3(512, 1, 1), blk, 0, stream>>>(qkvb, vt, yb);

  // out = yb @ wptT (fp32)
  gemm_out<<<dim3(CC / 128, (BB * TT) / 64), blk, 0, stream>>>(yb, wpt, out);
}

// Round 11
// 171.731 us; speedup vs baseline: 1.0834x; 1.0834x over previous
//
#include <hip/hip_runtime.h>
#include <hip/hip_bf16.h>
#include <math.h>

// Problem constants: B=2, T=2048, C=1024, H=16, D=64
#define BB 2
#define TT 2048
#define HH 16
#define DD 64
#define CC 1024
#define C3 3072

typedef __attribute__((ext_vector_type(8))) short bf16x8;
typedef __attribute__((ext_vector_type(4))) short bf16x4;
typedef __attribute__((ext_vector_type(4))) float f32x4;
typedef __attribute__((ext_vector_type(2))) unsigned int u32x2;

// round-to-nearest-even fp32 -> bf16 bits
__device__ __forceinline__ unsigned short f2bf(float f) {
  union { float f; unsigned u; } v; v.f = f;
  unsigned r = v.u + 0x7fffu + ((v.u >> 16) & 1u);
  return (unsigned short)(r >> 16);
}
// packed 2x fp32 -> bf16x2 (v_cvt_pk_bf16_f32 on gfx950), RNE
__device__ __forceinline__ unsigned pack2bf(float a, float b) {
  __hip_bfloat162 h = __float22bfloat162_rn(make_float2(a, b));
  union { __hip_bfloat162 h; unsigned u; } cv; cv.h = h;
  return cv.u;
}

// async global->LDS 16B copy (dest = wave-uniform base + lane*16)
__device__ __forceinline__ void async_cp16(const void* g, void* l) {
  __builtin_amdgcn_global_load_lds(
      (const __attribute__((address_space(1))) void*)g,
      (__attribute__((address_space(3))) void*)l, 16, 0, 0);
}

// ---------------------------------------------------------------------------
// prep: one launch does x->bf16 cvt + both weight transposes.
// ---------------------------------------------------------------------------
__global__ __launch_bounds__(256)
void prep(const float* __restrict__ x, const float* __restrict__ w_attn,
          const float* __restrict__ w_proj, unsigned short* __restrict__ xb,
          unsigned short* __restrict__ wat, unsigned short* __restrict__ wpt) {
  __shared__ __align__(16) float Ts[64][68];
  const int bx = blockIdx.x, tid = threadIdx.x;
  if (bx < 1024) {
    int i = bx * 256 + tid;
#pragma unroll
    for (int it = 0; it < 4; ++it, i += 262144) {
      const float4 v = ((const float4*)x)[i];
      bf16x4 o = {(short)f2bf(v.x), (short)f2bf(v.y),
                  (short)f2bf(v.z), (short)f2bf(v.w)};
      ((bf16x4*)xb)[i] = o;
    }
    return;
  }
  const float* W;
  unsigned short* WT;
  int Nd, bound, n0, k0;
  float s;
  if (bx < 1792) {
    const int bid = bx - 1024;
    W = w_attn; WT = wat; Nd = 3072; bound = 1024; s = 0.18033688f;  // 0.125*log2e
    n0 = (bid % 48) * 64; k0 = (bid / 48) * 64;
  } else {
    const int bid = bx - 1792;
    W = w_proj; WT = wpt; Nd = 1024; bound = 0; s = 1.0f;
    n0 = (bid % 16) * 64; k0 = (bid / 16) * 64;
  }
  const int rl = tid >> 4, c4 = tid & 15;
#pragma unroll
  for (int it = 0; it < 4; ++it) {
    const int r = it * 16 + rl;
    *(float4*)&Ts[r][c4 * 4] =
        *(const float4*)(W + (size_t)(k0 + r) * Nd + n0 + c4 * 4);
  }
  __syncthreads();
#pragma unroll
  for (int it = 0; it < 4; ++it) {
    const int n = it * 16 + rl;
    const float sc = (n0 + n < bound) ? s : 1.0f;
    bf16x4 o = {(short)f2bf(Ts[c4 * 4 + 0][n] * sc),
                (short)f2bf(Ts[c4 * 4 + 1][n] * sc),
                (short)f2bf(Ts[c4 * 4 + 2][n] * sc),
                (short)f2bf(Ts[c4 * 4 + 3][n] * sc)};
    *(bf16x4*)(WT + (size_t)(n0 + n) * CC + k0 + c4 * 4) = o;
  }
}

// ---------------------------------------------------------------------------
// gemm_qkv: qkv = xb(4096x1024) @ wat(3072x1024)^T.  Tile 128x128, BK=32,
// dbuf LDS (32 KB), grid 24x32 = 768 blocks = 3 blocks/CU (m97 occupancy).
// bf16 out; cols>=2048 (V) written transposed into vt[(b*16+h)*64+d][t].
// ---------------------------------------------------------------------------
__global__ __launch_bounds__(256, 3)
void gemm_qkv(const unsigned short* __restrict__ A,
              const unsigned short* __restrict__ BT,
              unsigned short* __restrict__ Cb,
              unsigned short* __restrict__ Vout) {
  __shared__ __align__(16) unsigned short As[2 * 128 * 32];  // 16 KB
  __shared__ __align__(16) unsigned short Bs[2 * 128 * 32];  // 16 KB

  const int tid = threadIdx.x;
  const int w = tid >> 6, lane = tid & 63;
  const int l15 = lane & 15, quad = lane >> 4;
  const int wm = w >> 1, wn = w & 1;
  const int row0 = blockIdx.y * 128, col0 = blockIdx.x * 128;

  // staging: chunk c -> row=c>>2, slot=c&3, src k=((c&3)^((c>>3)&3))*8
  const int ca0 = tid, ca1 = tid + 256;
  const int ra0 = ca0 >> 2, ka0 = ((ca0 & 3) ^ ((ca0 >> 3) & 3)) * 8;
  const int ra1 = ca1 >> 2, ka1 = ((ca1 & 3) ^ ((ca1 >> 3) & 3)) * 8;
  const unsigned short* gA0 = A + (size_t)(row0 + ra0) * CC + ka0;
  const unsigned short* gA1 = A + (size_t)(row0 + ra1) * CC + ka1;
  const unsigned short* gB0 = BT + (size_t)(col0 + ra0) * CC + ka0;
  const unsigned short* gB1 = BT + (size_t)(col0 + ra1) * CC + ka1;
  const int la0 = tid * 16, la1 = tid * 16 + 4096;

  // fragment read offset: row l15, slot quad^((l15>>1)&3)
  const int fro = l15 * 64 + 16 * (quad ^ ((l15 >> 1) & 3));

  f32x4 acc[4][4];
#pragma unroll
  for (int i = 0; i < 4; ++i)
#pragma unroll
    for (int j = 0; j < 4; ++j) acc[i][j] = (f32x4){0.f, 0.f, 0.f, 0.f};

  // prologue: stage tile 0 into buf 0
  async_cp16(gA0, (char*)As + la0);
  async_cp16(gA1, (char*)As + la1);
  async_cp16(gB0, (char*)Bs + la0);
  async_cp16(gB1, (char*)Bs + la1);

  for (int i = 0; i < 32; ++i) {
    const int cur = i & 1;
    __syncthreads();

    if (i + 1 < 32) {
      const int k1 = (i + 1) * 32;
      const int ab = (cur ^ 1) * 8192;
      async_cp16(gA0 + k1, (char*)As + ab + la0);
      async_cp16(gA1 + k1, (char*)As + ab + la1);
      async_cp16(gB0 + k1, (char*)Bs + ab + la0);
      async_cp16(gB1 + k1, (char*)Bs + ab + la1);
    }

    const char* fA = (const char*)As + cur * 8192 + wm * 4096 + fro;
    const char* fB = (const char*)Bs + cur * 8192 + wn * 4096 + fro;

    bf16x8 af[4], bf[4];
#pragma unroll
    for (int mt = 0; mt < 4; ++mt) af[mt] = *(const bf16x8*)(fA + mt * 1024);
#pragma unroll
    for (int nt = 0; nt < 4; ++nt) bf[nt] = *(const bf16x8*)(fB + nt * 1024);
#pragma unroll
    for (int mt = 0; mt < 4; ++mt)
#pragma unroll
      for (int nt = 0; nt < 4; ++nt)
        acc[mt][nt] = __builtin_amdgcn_mfma_f32_16x16x32_bf16(
            af[mt], bf[nt], acc[mt][nt], 0, 0, 0);
  }

  if (col0 >= 2048) {
    // V region: write transposed into vt[(b*1024)+(col-2048)][t]
#pragma unroll
    for (int mt = 0; mt < 4; ++mt) {
      const int rbase = row0 + wm * 64 + mt * 16 + quad * 4;
      const int bq = rbase >> 11, t0 = rbase & 2047;
#pragma unroll
      for (int nt = 0; nt < 4; ++nt) {
        const int d = col0 + wn * 64 + nt * 16 + l15 - 2048;
        bf16x4 o = {(short)f2bf(acc[mt][nt][0]), (short)f2bf(acc[mt][nt][1]),
                    (short)f2bf(acc[mt][nt][2]), (short)f2bf(acc[mt][nt][3])};
        *(bf16x4*)(Vout + (((size_t)(bq << 10) + d) << 11) + t0) = o;
      }
    }
  } else {
#pragma unroll
    for (int mt = 0; mt < 4; ++mt) {
      const int rbase = row0 + wm * 64 + mt * 16 + quad * 4;
#pragma unroll
      for (int r = 0; r < 4; ++r) {
        unsigned short* cr =
            Cb + (size_t)(rbase + r) * C3 + col0 + wn * 64 + l15;
#pragma unroll
        for (int nt = 0; nt < 4; ++nt) cr[nt * 16] = f2bf(acc[mt][nt][r]);
      }
    }
  }
}

// ---------------------------------------------------------------------------
// gemm_out: out(4096x1024 fp32) = yb(4096x1024) @ wpt(1024x1024)^T.
// Tile 64x128, BK=64 (16 iters x 16 MFMA/wave), waves 2x2, dbuf LDS.
// ---------------------------------------------------------------------------
__global__ __launch_bounds__(256, 2)
void gemm_out(const unsigned short* __restrict__ A,
              const unsigned short* __restrict__ BT,
              float* __restrict__ Cf) {
  __shared__ __align__(16) unsigned short As[2 * 64 * 64];    // 16 KB
  __shared__ __align__(16) unsigned short Bs[2 * 128 * 64];   // 32 KB

  const int tid = threadIdx.x;
  const int w = tid >> 6, lane = tid & 63;
  const int l15 = lane & 15, quad = lane >> 4;
  const int wm = w >> 1, wn = w & 1;
  const int row0 = blockIdx.y * 64, col0 = blockIdx.x * 128;

  const int ca0 = tid, ca1 = tid + 256;
  const int ra0 = ca0 >> 3, ka0 = ((ca0 & 7) ^ ((ca0 >> 3) & 7)) * 8;
  const int ra1 = ca1 >> 3, ka1 = ((ca1 & 7) ^ ((ca1 >> 3) & 7)) * 8;
  const unsigned short* gA0 = A + (size_t)(row0 + ra0) * CC + ka0;
  const unsigned short* gA1 = A + (size_t)(row0 + ra1) * CC + ka1;
  const unsigned short* gB[4];
  int lb[4];
#pragma unroll
  for (int t = 0; t < 4; ++t) {
    const int c = tid + t * 256;
    const int rb = c >> 3, kb = ((c & 7) ^ ((c >> 3) & 7)) * 8;
    gB[t] = BT + (size_t)(col0 + rb) * CC + kb;
    lb[t] = c * 16;
  }
  const int la0 = tid * 16, la1 = tid * 16 + 4096;

  const int fro = l15 * 128 + ((quad ^ (l15 & 7)) << 4);

  f32x4 acc[2][4];
#pragma unroll
  for (int i = 0; i < 2; ++i)
#pragma unroll
    for (int j = 0; j < 4; ++j) acc[i][j] = (f32x4){0.f, 0.f, 0.f, 0.f};

  async_cp16(gA0, (char*)As + la0);
  async_cp16(gA1, (char*)As + la1);
#pragma unroll
  for (int t = 0; t < 4; ++t) async_cp16(gB[t], (char*)Bs + lb[t]);

  for (int i = 0; i < 16; ++i) {
    const int cur = i & 1;
    __syncthreads();

    if (i + 1 < 16) {
      const int k1 = (i + 1) * 64;
      const int ab = (cur ^ 1) * 8192, bb = (cur ^ 1) * 16384;
      async_cp16(gA0 + k1, (char*)As + ab + la0);
      async_cp16(gA1 + k1, (char*)As + ab + la1);
#pragma unroll
      for (int t = 0; t < 4; ++t) async_cp16(gB[t] + k1, (char*)Bs + bb + lb[t]);
    }

    const char* fA = (const char*)As + cur * 8192 + wm * 4096 + fro;
    const char* fB = (const char*)Bs + cur * 16384 + wn * 8192 + fro;

#pragma unroll
    for (int kh = 0; kh < 2; ++kh) {
      const int xo = kh * 64;
      bf16x8 af[2], bf[4];
#pragma unroll
      for (int mt = 0; mt < 2; ++mt)
        af[mt] = *(const bf16x8*)(fA + mt * 2048 + ((fro + xo) & 127) - (fro & 127));
#pragma unroll
      for (int nt = 0; nt < 4; ++nt)
        bf[nt] = *(const bf16x8*)(fB + nt * 2048 + ((fro + xo) & 127) - (fro & 127));
#pragma unroll
      for (int mt = 0; mt < 2; ++mt)
#pragma unroll
        for (int nt = 0; nt < 4; ++nt)
          acc[mt][nt] = __builtin_amdgcn_mfma_f32_16x16x32_bf16(
              af[mt], bf[nt], acc[mt][nt], 0, 0, 0);
    }
  }

#pragma unroll
  for (int mt = 0; mt < 2; ++mt) {
    const int rbase = row0 + wm * 32 + mt * 16 + quad * 4;
#pragma unroll
    for (int r = 0; r < 4; ++r) {
      float* cr = Cf + (size_t)(rbase + r) * CC + col0 + wn * 64 + l15;
#pragma unroll
      for (int nt = 0; nt < 4; ++nt) cr[nt * 16] = acc[mt][nt][r];
    }
  }
}

// ---------------------------------------------------------------------------
// MFMA flash attention, round-11: round-9 single-stream loop (proven) +
// ct-XOR swizzled Ps (no bank conflicts) + packed bf16 cvt + RAW v_exp_f32
// (__builtin_amdgcn_exp2f — libm exp2f's guard sequence was ~10 VALU/call).
// Transposed dataflow, XCD-aware grid, q-tile pairing, dbuf K/V staging,
// fixed-max base-2 softmax (bias -12 in MFMA C-init) unchanged.
// ---------------------------------------------------------------------------
__global__ __launch_bounds__(256)
void attn_mfma(const unsigned short* __restrict__ qkvb,
               const unsigned short* __restrict__ vt,
               unsigned short* __restrict__ y) {
  const int n = blockIdx.x;
  const int bh = (n & 7) + 8 * ((n >> 3) & 3);
  const int qpair = n >> 5;
  const int b = bh >> 4, h = bh & 15;
  const int tid = threadIdx.x;
  const int w = tid >> 6;
  const int lane = tid & 63;
  const int l15 = lane & 15, quad = lane >> 4;

  __shared__ __align__(16) char Kb[2 * 8192];
  __shared__ __align__(16) char Vb[2 * 8192];
  __shared__ __align__(16) unsigned short Ps[4 * 16 * 72];
  char* psw = (char*)(Ps + w * 16 * 72);

  const int lr = lane >> 3;
  const int lc = lane & 7;
  const int srcoff = ((lc ^ lr) << 4);
  const char* ksrc = (const char*)qkvb + ((size_t)(b * TT) * C3 + 1024 + h * 64) * 2;
  const char* vsrc = (const char*)vt + ((size_t)(b * HH + h) * DD * TT) * 2;

  const int fro = l15 * 128 + ((quad ^ (l15 & 7)) << 4);

  // Ps addressing (ct-XOR swizzle)
  const int psrow = l15 * 144;

  bf16x8 onesf;
#pragma unroll
  for (int jj = 0; jj < 8; ++jj) onesf[jj] = (short)0x3F80;

  for (int phase = 0; phase < 2; ++phase) {
    const int qt = phase == 0 ? 31 - qpair : qpair;

    if (phase) __syncthreads();

    const unsigned short* qrow =
        qkvb + (size_t)(b * TT + qt * 64 + w * 16 + l15) * C3 + h * DD;
    bf16x8 qf0 = *(const bf16x8*)(qrow + quad * 8);
    bf16x8 qf1 = *(const bf16x8*)(qrow + 32 + quad * 8);

    f32x4 O[4];
#pragma unroll
    for (int dt = 0; dt < 4; ++dt) O[dt] = (f32x4){0.f, 0.f, 0.f, 0.f};
    f32x4 lacc = (f32x4){0.f, 0.f, 0.f, 0.f};

#pragma unroll
    for (int i = 0; i < 2; ++i) {
      async_cp16(ksrc + (size_t)(w * 16 + i * 8 + lr) * (C3 * 2) + srcoff,
                 Kb + w * 2048 + i * 1024);
      async_cp16(vsrc + (size_t)(w * 16 + i * 8 + lr) * (TT * 2) + srcoff,
                 Vb + w * 2048 + i * 1024);
    }

    for (int j = 0; j <= qt; ++j) {
      const int cur = j & 1;
      __syncthreads();  // tile j staged; reads of buf cur^1 done

      if (j < qt) {
        const int key1 = (j + 1) * 64;
        char* kd = Kb + (cur ^ 1) * 8192 + w * 2048;
        char* vd = Vb + (cur ^ 1) * 8192 + w * 2048;
#pragma unroll
        for (int i = 0; i < 2; ++i) {
          async_cp16(
              ksrc + (size_t)(key1 + w * 16 + i * 8 + lr) * (C3 * 2) + srcoff,
              kd + i * 1024);
          async_cp16(
              vsrc + (size_t)(w * 16 + i * 8 + lr) * (TT * 2) + key1 * 2 + srcoff,
              vd + i * 1024);
        }
      }

      const char* Kc = Kb + cur * 8192;
      const char* Vc = Vb + cur * 8192;

      // ---- S^T = K Q^T - 12 ----
      f32x4 S[4];
#pragma unroll
      for (int ct = 0; ct < 4; ++ct) {
        bf16x8 k0 = *(const bf16x8*)(Kc + ct * 2048 + fro);
        bf16x8 k1 = *(const bf16x8*)(Kc + ct * 2048 + (fro ^ 64));
        f32x4 z = (f32x4){-12.f, -12.f, -12.f, -12.f};
        z = __builtin_amdgcn_mfma_f32_16x16x32_bf16(k0, qf0, z, 0, 0, 0);
        z = __builtin_amdgcn_mfma_f32_16x16x32_bf16(k1, qf1, z, 0, 0, 0);
        S[ct] = z;
      }

      if (j == qt) {  // causal mask on diagonal tile
#pragma unroll
        for (int ct = 0; ct < 4; ++ct)
#pragma unroll
          for (int r = 0; r < 4; ++r)
            if (16 * ct + quad * 4 + r > w * 16 + l15) S[ct][r] = -INFINITY;
      }

      // ---- P^T = exp2(S^T) via raw v_exp_f32; pack -> swizzled Ps ----
#pragma unroll
      for (int ct = 0; ct < 4; ++ct) {
        u32x2 d;
        d[0] = pack2bf(__builtin_amdgcn_exp2f(S[ct][0]),
                       __builtin_amdgcn_exp2f(S[ct][1]));
        d[1] = pack2bf(__builtin_amdgcn_exp2f(S[ct][2]),
                       __builtin_amdgcn_exp2f(S[ct][3]));
        *(u32x2*)(psw + psrow + (((ct + l15) & 3) << 5) + quad * 8) = d;
      }

      bf16x8 pf0, pf1;
      {
        const int c0 = (quad >> 1), c1 = 2 + (quad >> 1);
        pf0 = *(const bf16x8*)(psw + psrow + (((c0 + l15) & 3) << 5) + ((quad & 1) << 4));
        pf1 = *(const bf16x8*)(psw + psrow + (((c1 + l15) & 3) << 5) + ((quad & 1) << 4));
      }

      // ---- l[q] += colsum(P^T); O^T += V^T P^T ----
      lacc = __builtin_amdgcn_mfma_f32_16x16x32_bf16(onesf, pf0, lacc, 0, 0, 0);
      lacc = __builtin_amdgcn_mfma_f32_16x16x32_bf16(onesf, pf1, lacc, 0, 0, 0);
#pragma unroll
      for (int dt = 0; dt < 4; ++dt) {
        bf16x8 v0 = *(const bf16x8*)(Vc + dt * 2048 + fro);
        bf16x8 v1 = *(const bf16x8*)(Vc + dt * 2048 + (fro ^ 64));
        O[dt] = __builtin_amdgcn_mfma_f32_16x16x32_bf16(v0, pf0, O[dt], 0, 0, 0);
        O[dt] = __builtin_amdgcn_mfma_f32_16x16x32_bf16(v1, pf1, O[dt], 0, 0, 0);
      }
    }

    // ---- epilogue: lane holds O^T[d=dt*16+quad*4+r][q=l15]; l in lacc ----
    const float inv = 1.0f / lacc[0];
    unsigned short* yr =
        y + (size_t)(b * TT + qt * 64 + w * 16 + l15) * CC + h * DD + quad * 4;
#pragma unroll
    for (int dt = 0; dt < 4; ++dt) {
      bf16x4 o = {(short)f2bf(O[dt][0] * inv), (short)f2bf(O[dt][1] * inv),
                  (short)f2bf(O[dt][2] * inv), (short)f2bf(O[dt][3] * inv)};
      *(bf16x4*)(yr + dt * 16) = o;
    }
  }
}

// ---------------------------------------------------------------------------
extern "C" void kernel_launch(void* const* d_in, const int* in_sizes, int n_in,
                              void* d_out, int out_size, void* d_ws,
                              size_t ws_size, hipStream_t stream) {
  const float* x      = (const float*)d_in[0];
  const float* w_attn = (const float*)d_in[1];
  const float* w_proj = (const float*)d_in[2];
  float* out = (float*)d_out;

  unsigned short* xb   = (unsigned short*)d_ws;
  unsigned short* wat  = xb + (size_t)4096 * 1024;
  unsigned short* wpt  = wat + (size_t)3072 * 1024;
  unsigned short* qkvb = wpt + (size_t)1024 * 1024;
  unsigned short* vt   = qkvb + (size_t)4096 * 3072;
  unsigned short* yb   = vt + (size_t)BB * HH * DD * TT;

  dim3 blk(256);

  prep<<<2048, blk, 0, stream>>>(x, w_attn, w_proj, xb, wat, wpt);

  // qkv = xb @ watT; q pre-scaled via wat; v written transposed into vt
  gemm_qkv<<<dim3(C3 / 128, (BB * TT) / 128), blk, 0, stream>>>(
      xb, wat, qkvb, vt);

  attn_mfma<<<dim3(512, 1, 1), blk, 0, stream>>>(qkvb, vt, yb);

  // out = yb @ wptT (fp32)
  gemm_out<<<dim3(CC / 128, (BB * TT) / 64), blk, 0, stream>>>(yb, wpt, out);
}